// Round 1
// baseline (1353.814 us; speedup 1.0000x reference)
//
#include <hip/hip_runtime.h>
#include <hip/hip_bf16.h>

typedef __bf16 bf16_t;
typedef __bf16 bf16x8 __attribute__((ext_vector_type(8)));
typedef __bf16 bf16x4 __attribute__((ext_vector_type(4)));
typedef float  f32x4  __attribute__((ext_vector_type(4)));

#define MFMA16(A, B, C) __builtin_amdgcn_mfma_f32_16x16x32_bf16((A), (B), (C), 0, 0, 0)

// ---------------- geometry ----------------
// B_=4096 windows, N=64 tokens, C=256 channels, H=8 heads, Dh=32, nW=64 masks.

// ---------------- LDS layout (bytes) ----------------
// Xl  : [64][264] bf16  = 33792   (x tile, stride 264 -> 528B rows, 2-way bank alias only)
// AO  : [64][264] bf16  = 33792   (attention output tile, all heads)
// per-wave (x4): QN [64][40] bf16 (5120) ; KN [64][40] (5120) ; VT [32][72] (4608)
//               P  [64][72] bf16 (9216) overlaps QN+KN (dead by then)
static constexpr int XL_STRIDE = 264;
static constexpr int AO_OFF    = 64 * 264 * 2;           // 33792
static constexpr int AO_STRIDE = 264;
static constexpr int WB_OFF    = AO_OFF + 64 * 264 * 2;  // 67584
static constexpr int QN_STRIDE = 40;
static constexpr int KN_OFF    = 64 * 40 * 2;            // 5120
static constexpr int VT_OFF    = 2 * KN_OFF;             // 10240
static constexpr int VT_STRIDE = 72;
static constexpr int P_STRIDE  = 72;
static constexpr int WB_BYTES  = VT_OFF + 32 * 72 * 2;   // 14848
static constexpr int LDS_TOTAL = WB_OFF + 4 * WB_BYTES;  // 126976

// ---------------- workspace layout ----------------
// [0 .. 524288)          : bf16 weights, qkv_w (768*256) then proj_w (256*256)
// [524288 .. 524288+4064): float bias16[8][127]  (16*sigmoid(cpb MLP) LUT)
static constexpr int WS_BIAS_OFF = (768 * 256 + 256 * 256) * 2;  // 524288

// ============ kernel 0: fp32 -> bf16 weight conversion ============
__global__ void cvt_weights(const float* __restrict__ qkv_w,
                            const float* __restrict__ proj_w,
                            bf16_t* __restrict__ dst) {
    const int i4 = blockIdx.x * blockDim.x + threadIdx.x;  // 0..65535 float4s
    float4 v;
    if (i4 < 49152) v = ((const float4*)qkv_w)[i4];
    else            v = ((const float4*)proj_w)[i4 - 49152];
    bf16x4 p = { (bf16_t)v.x, (bf16_t)v.y, (bf16_t)v.z, (bf16_t)v.w };
    ((bf16x4*)dst)[i4] = p;
}

// ============ kernel 1: CPB MLP -> 16*sigmoid LUT [8][127] ============
__global__ void cpb_table(const float* __restrict__ rel_table,
                          const float* __restrict__ w1,
                          const float* __restrict__ b1,
                          const float* __restrict__ w2,
                          float* __restrict__ bias16) {
    const int t    = blockIdx.x;    // 0..126
    const int lane = threadIdx.x;   // 0..63
    const float rt = rel_table[t];
    float acc[8];
#pragma unroll
    for (int h = 0; h < 8; ++h) acc[h] = 0.f;
    for (int c = lane; c < 512; c += 64) {
        const float hv = fmaxf(rt * w1[c] + b1[c], 0.f);
#pragma unroll
        for (int h = 0; h < 8; ++h) acc[h] += hv * w2[h * 512 + c];
    }
#pragma unroll
    for (int h = 0; h < 8; ++h) {
#pragma unroll
        for (int d = 1; d < 64; d <<= 1) acc[h] += __shfl_xor(acc[h], d);
    }
    if (lane == 0) {
#pragma unroll
        for (int h = 0; h < 8; ++h)
            bias16[h * 127 + t] = 16.f / (1.f + __expf(-acc[h]));
    }
}

// ============ main fused window-attention kernel ============
// grid 256 (persistent, 1 block/CU at 124KB LDS), block 256 (4 waves).
// wave wv handles heads {2wv, 2wv+1}. 16 windows per block.
__global__ __launch_bounds__(256, 1)
void wattn_kernel(const float* __restrict__ x,
                  const float* __restrict__ mask,
                  const float* __restrict__ q_bias,
                  const float* __restrict__ v_bias,
                  const float* __restrict__ logit_scale,
                  const float* __restrict__ proj_b,
                  const bf16_t* __restrict__ wbf,
                  const float* __restrict__ bias16,
                  float* __restrict__ out) {
    extern __shared__ __align__(16) char smem[];
    bf16_t* Xl = (bf16_t*)smem;
    bf16_t* AO = (bf16_t*)(smem + AO_OFF);

    const int tid  = threadIdx.x;
    const int wv   = tid >> 6;
    const int lane = tid & 63;
    const int quad = lane >> 4;
    const int l16  = lane & 15;

    char*   wbase = smem + WB_OFF + wv * WB_BYTES;
    bf16_t* QN = (bf16_t*)wbase;
    bf16_t* KN = (bf16_t*)(wbase + KN_OFF);
    bf16_t* VT = (bf16_t*)(wbase + VT_OFF);
    bf16_t* Pm = (bf16_t*)wbase;  // overlaps QN+KN (they are dead when P is written)

    const bf16_t* qkvw  = wbf;
    const bf16_t* projw = wbf + 768 * 256;

    const f32x4 fz = {0.f, 0.f, 0.f, 0.f};
    const int w0 = blockIdx.x * 16;

    // ---- prologue: load + stage X(w0) ----
    float4 xf[16];
    {
        const float4* src = (const float4*)(x + (size_t)w0 * (64 * 256));
#pragma unroll
        for (int j = 0; j < 16; ++j) xf[j] = src[j * 256 + tid];
#pragma unroll
        for (int j = 0; j < 16; ++j) {
            const int e = (j * 256 + tid) * 4;
            const int r = e >> 8, c = e & 255;
            bf16x4 p = { (bf16_t)xf[j].x, (bf16_t)xf[j].y, (bf16_t)xf[j].z, (bf16_t)xf[j].w };
            *(bf16x4*)(Xl + r * XL_STRIDE + c) = p;
        }
    }
    __syncthreads();

    for (int it = 0; it < 16; ++it) {
        const int w = w0 + it;
        const bool havenext = (it < 15);
        // prefetch next window's X into VGPRs (occupancy-1 -> 512 VGPR budget)
        if (havenext) {
            const float4* src = (const float4*)(x + (size_t)(w + 1) * (64 * 256));
#pragma unroll
            for (int j = 0; j < 16; ++j) xf[j] = src[j * 256 + tid];
        }

        const float* mrow = mask + (size_t)(w & 63) * (64 * 64);

        for (int hi = 0; hi < 2; ++hi) {
            const int h = wv * 2 + hi;
            const float scale_h = __expf(fminf(logit_scale[h], 4.6051701859880914f));

            // ---------- QKV GEMM: q/k/v (64x32 each) = X(64x256) @ W^T ----------
            f32x4 qa[4][2], ka[4][2], va[4][2];
#pragma unroll
            for (int mt = 0; mt < 4; ++mt)
#pragma unroll
                for (int nt = 0; nt < 2; ++nt) { qa[mt][nt] = fz; ka[mt][nt] = fz; va[mt][nt] = fz; }

            const bf16_t* wqp = qkvw + (0   + h * 32) * 256;
            const bf16_t* wkp = qkvw + (256 + h * 32) * 256;
            const bf16_t* wvp = qkvw + (512 + h * 32) * 256;
#pragma unroll
            for (int ks = 0; ks < 8; ++ks) {
                bf16x8 af[4];
#pragma unroll
                for (int mt = 0; mt < 4; ++mt)
                    af[mt] = *(const bf16x8*)(Xl + (mt * 16 + l16) * XL_STRIDE + ks * 32 + quad * 8);
#pragma unroll
                for (int nt = 0; nt < 2; ++nt) {
                    const int ro = (nt * 16 + l16) * 256 + ks * 32 + quad * 8;
                    bf16x8 bq = *(const bf16x8*)(wqp + ro);
                    bf16x8 bk = *(const bf16x8*)(wkp + ro);
                    bf16x8 bv = *(const bf16x8*)(wvp + ro);
#pragma unroll
                    for (int mt = 0; mt < 4; ++mt) {
                        qa[mt][nt] = MFMA16(af[mt], bq, qa[mt][nt]);
                        ka[mt][nt] = MFMA16(af[mt], bk, ka[mt][nt]);
                        va[mt][nt] = MFMA16(af[mt], bv, va[mt][nt]);
                    }
                }
            }
            // biases (k has none per reference concat [q_bias, 0, v_bias])
#pragma unroll
            for (int nt = 0; nt < 2; ++nt) {
                const float qb = q_bias[h * 32 + nt * 16 + l16];
                const float vb = v_bias[h * 32 + nt * 16 + l16];
#pragma unroll
                for (int mt = 0; mt < 4; ++mt)
#pragma unroll
                    for (int j = 0; j < 4; ++j) { qa[mt][nt][j] += qb; va[mt][nt][j] += vb; }
            }

            // ---------- l2norm rows of q,k (fold scale into q); stage QN/KN/VT ----------
#pragma unroll
            for (int mt = 0; mt < 4; ++mt) {
                float sq[4], sk[4];
#pragma unroll
                for (int j = 0; j < 4; ++j) {
                    sq[j] = qa[mt][0][j] * qa[mt][0][j] + qa[mt][1][j] * qa[mt][1][j];
                    sk[j] = ka[mt][0][j] * ka[mt][0][j] + ka[mt][1][j] * ka[mt][1][j];
                }
#pragma unroll
                for (int j = 0; j < 4; ++j) {
#pragma unroll
                    for (int d = 1; d < 16; d <<= 1) {
                        sq[j] += __shfl_xor(sq[j], d);
                        sk[j] += __shfl_xor(sk[j], d);
                    }
                    sq[j] = scale_h * rsqrtf(fmaxf(sq[j], 1e-24f));
                    sk[j] = rsqrtf(fmaxf(sk[j], 1e-24f));
                }
#pragma unroll
                for (int nt = 0; nt < 2; ++nt)
#pragma unroll
                    for (int j = 0; j < 4; ++j) {
                        const int r = mt * 16 + quad * 4 + j;
                        QN[r * QN_STRIDE + nt * 16 + l16] = (bf16_t)(qa[mt][nt][j] * sq[j]);
                        KN[r * QN_STRIDE + nt * 16 + l16] = (bf16_t)(ka[mt][nt][j] * sk[j]);
                    }
#pragma unroll
                for (int nt = 0; nt < 2; ++nt) {
                    bf16x4 pv = { (bf16_t)va[mt][nt][0], (bf16_t)va[mt][nt][1],
                                  (bf16_t)va[mt][nt][2], (bf16_t)va[mt][nt][3] };
                    *(bf16x4*)(VT + (nt * 16 + l16) * VT_STRIDE + mt * 16 + quad * 4) = pv;  // transposed: VT[d][token]
                }
            }

            // ---------- attn = (qn*scale) @ kn^T  (K=32, one MFMA per 16x16 tile) ----------
            bf16x8 aq[4], bkf[4];
#pragma unroll
            for (int mt = 0; mt < 4; ++mt)
                aq[mt] = *(const bf16x8*)(QN + (mt * 16 + l16) * QN_STRIDE + quad * 8);
#pragma unroll
            for (int nt2 = 0; nt2 < 4; ++nt2)
                bkf[nt2] = *(const bf16x8*)(KN + (nt2 * 16 + l16) * QN_STRIDE + quad * 8);

            f32x4 sfr[4][4];
#pragma unroll
            for (int mt = 0; mt < 4; ++mt)
#pragma unroll
                for (int nt2 = 0; nt2 < 4; ++nt2)
                    sfr[mt][nt2] = MFMA16(aq[mt], bkf[nt2], fz);

            // + relative position bias (LUT on r-c) + window mask
            const float* brow = bias16 + h * 127;
#pragma unroll
            for (int mt = 0; mt < 4; ++mt)
#pragma unroll
                for (int j = 0; j < 4; ++j) {
                    const int r = mt * 16 + quad * 4 + j;
#pragma unroll
                    for (int nt2 = 0; nt2 < 4; ++nt2) {
                        const int c = nt2 * 16 + l16;
                        sfr[mt][nt2][j] += brow[r - c + 63] + mrow[r * 64 + c];
                    }
                }

            // ---------- softmax over the 64 keys (quad-group butterfly) ----------
            float rinv[4][4];
#pragma unroll
            for (int mt = 0; mt < 4; ++mt)
#pragma unroll
                for (int j = 0; j < 4; ++j) {
                    float mx = fmaxf(fmaxf(sfr[mt][0][j], sfr[mt][1][j]),
                                     fmaxf(sfr[mt][2][j], sfr[mt][3][j]));
#pragma unroll
                    for (int d = 1; d < 16; d <<= 1) mx = fmaxf(mx, __shfl_xor(mx, d));
                    float sum = 0.f;
#pragma unroll
                    for (int nt2 = 0; nt2 < 4; ++nt2) {
                        const float e = __expf(sfr[mt][nt2][j] - mx);
                        sfr[mt][nt2][j] = e;
                        sum += e;
                    }
#pragma unroll
                    for (int d = 1; d < 16; d <<= 1) sum += __shfl_xor(sum, d);
                    rinv[mt][j] = 1.0f / sum;
                    const int r = mt * 16 + quad * 4 + j;
#pragma unroll
                    for (int nt2 = 0; nt2 < 4; ++nt2)
                        Pm[r * P_STRIDE + nt2 * 16 + l16] = (bf16_t)sfr[mt][nt2][j];  // unnormalized exp
                }

            // ---------- PV: out_h(64x32) = P(64x64) @ V(64x32), normalize after ----------
            bf16x8 bvf[2][2];
#pragma unroll
            for (int nt = 0; nt < 2; ++nt)
#pragma unroll
                for (int k2 = 0; k2 < 2; ++k2)
                    bvf[nt][k2] = *(const bf16x8*)(VT + (nt * 16 + l16) * VT_STRIDE + k2 * 32 + quad * 8);
            f32x4 oa[4][2];
#pragma unroll
            for (int mt = 0; mt < 4; ++mt)
#pragma unroll
                for (int nt = 0; nt < 2; ++nt) oa[mt][nt] = fz;
#pragma unroll
            for (int mt = 0; mt < 4; ++mt) {
#pragma unroll
                for (int k2 = 0; k2 < 2; ++k2) {
                    bf16x8 ap = *(const bf16x8*)(Pm + (mt * 16 + l16) * P_STRIDE + k2 * 32 + quad * 8);
#pragma unroll
                    for (int nt = 0; nt < 2; ++nt)
                        oa[mt][nt] = MFMA16(ap, bvf[nt][k2], oa[mt][nt]);
                }
            }
            // write AO columns h*32..h*32+31 (bf16)
#pragma unroll
            for (int mt = 0; mt < 4; ++mt)
#pragma unroll
                for (int nt = 0; nt < 2; ++nt)
#pragma unroll
                    for (int j = 0; j < 4; ++j) {
                        const int r = mt * 16 + quad * 4 + j;
                        AO[r * AO_STRIDE + h * 32 + nt * 16 + l16] = (bf16_t)(oa[mt][nt][j] * rinv[mt][j]);
                    }
        }  // hi

        __syncthreads();  // B1: AO complete for all heads; all Xl reads done

        // stage prefetched X(w+1) into Xl (overlaps proj compute)
        if (havenext) {
#pragma unroll
            for (int j = 0; j < 16; ++j) {
                const int e = (j * 256 + tid) * 4;
                const int r = e >> 8, c = e & 255;
                bf16x4 p = { (bf16_t)xf[j].x, (bf16_t)xf[j].y, (bf16_t)xf[j].z, (bf16_t)xf[j].w };
                *(bf16x4*)(Xl + r * XL_STRIDE + c) = p;
            }
        }

        // ---------- proj: out(64x256) = AO(64x256) @ proj_w^T + proj_b ----------
        // wave wv owns output cols [wv*64, wv*64+64)
        f32x4 pacc[4][4];
#pragma unroll
        for (int mt = 0; mt < 4; ++mt)
#pragma unroll
            for (int j4 = 0; j4 < 4; ++j4) pacc[mt][j4] = fz;
        const bf16_t* pw = projw + (wv * 64) * 256;
#pragma unroll
        for (int ks = 0; ks < 8; ++ks) {
            bf16x8 af[4];
#pragma unroll
            for (int mt = 0; mt < 4; ++mt)
                af[mt] = *(const bf16x8*)(AO + (mt * 16 + l16) * AO_STRIDE + ks * 32 + quad * 8);
#pragma unroll
            for (int j4 = 0; j4 < 4; ++j4) {
                bf16x8 bw = *(const bf16x8*)(pw + (j4 * 16 + l16) * 256 + ks * 32 + quad * 8);
#pragma unroll
                for (int mt = 0; mt < 4; ++mt)
                    pacc[mt][j4] = MFMA16(af[mt], bw, pacc[mt][j4]);
            }
        }
        float* obase = out + (size_t)w * (64 * 256);
#pragma unroll
        for (int j4 = 0; j4 < 4; ++j4) {
            const int col = wv * 64 + j4 * 16 + l16;
            const float pb = proj_b[col];
#pragma unroll
            for (int mt = 0; mt < 4; ++mt)
#pragma unroll
                for (int j = 0; j < 4; ++j) {
                    const int r = mt * 16 + quad * 4 + j;
                    obase[r * 256 + col] = pacc[mt][j4][j] + pb;
                }
        }
        __syncthreads();  // B2: AO free for next window; Xl staged for next window
    }  // it
}

extern "C" void kernel_launch(void* const* d_in, const int* in_sizes, int n_in,
                              void* d_out, int out_size, void* d_ws, size_t ws_size,
                              hipStream_t stream) {
    const float* x           = (const float*)d_in[0];
    const float* mask        = (const float*)d_in[1];
    const float* qkv_w       = (const float*)d_in[2];
    const float* q_bias      = (const float*)d_in[3];
    const float* v_bias      = (const float*)d_in[4];
    const float* logit_scale = (const float*)d_in[5];
    const float* cpb_w1      = (const float*)d_in[6];
    const float* cpb_b1      = (const float*)d_in[7];
    const float* cpb_w2      = (const float*)d_in[8];
    const float* proj_w      = (const float*)d_in[9];
    const float* proj_b      = (const float*)d_in[10];
    const float* rel_table   = (const float*)d_in[11];
    // d_in[12] = rel_index: analytically i - j + 63, not needed on device.
    float* out = (float*)d_out;

    bf16_t* wbf    = (bf16_t*)d_ws;
    float*  bias16 = (float*)((char*)d_ws + WS_BIAS_OFF);

    // ws re-poisoned each timed call -> regenerate every launch
    cvt_weights<<<dim3(256), dim3(256), 0, stream>>>(qkv_w, proj_w, wbf);
    cpb_table<<<dim3(127), dim3(64), 0, stream>>>(rel_table, cpb_w1, cpb_b1, cpb_w2, bias16);

    // opt-in to >64KB dynamic LDS (idempotent, capture-safe host call)
    (void)hipFuncSetAttribute((const void*)wattn_kernel,
                              hipFuncAttributeMaxDynamicSharedMemorySize, LDS_TOTAL);
    wattn_kernel<<<dim3(256), dim3(256), LDS_TOTAL, stream>>>(
        x, mask, q_bias, v_bias, logit_scale, proj_b, wbf, bias16, out);
}